// Round 10
// baseline (105.889 us; speedup 1.0000x reference)
//
#include <hip/hip_runtime.h>
#include <math.h>

// N=512, IN_F=128, OUT_F=64, H=4.
// SINGLE-KERNEL pipeline (plus a 4-byte memset node for the barrier counter).
// 256 blocks x 512 thr, 1 block/CU -> all blocks co-resident, so a global
// arrival-counter barrier is deadlock-free (cheap vs cg::grid.sync's ~40us).
// Phase A: ht=h@W^T (rows 2b,2b+1) -> htb bf16 j-pair pack + s1(LDS) + s2(global)
//          + Ub/Vb bf16 pack + adj/ew -> ewm/bias prefetch (hidden under barrier).
// Phase B: in-register softmax (alpha f32 in LDS) -> bf16 aggregate -> c(LDS)
//          -> bf16 U/V epilogue -> sigmoid -> out.

__device__ __forceinline__ float wave_sum(float v) {
    #pragma unroll
    for (int o = 32; o; o >>= 1) v += __shfl_xor(v, o, 64);
    return v;
}
__device__ __forceinline__ float wave_max(float v) {
    #pragma unroll
    for (int o = 32; o; o >>= 1) v = fmaxf(v, __shfl_xor(v, o, 64));
    return v;
}
__device__ __forceinline__ unsigned bf16rn(float x) {   // round-to-nearest-even bf16
    unsigned u = __float_as_uint(x);
    return (u + 0x7fffu + ((u >> 16) & 1u)) >> 16;
}
__device__ __forceinline__ float asf(unsigned u) { return __uint_as_float(u); }

__global__ __launch_bounds__(512) void k_mono(
    const float* __restrict__ h, const int* __restrict__ adj,
    const float* __restrict__ ew, const float* __restrict__ W,
    const float* __restrict__ a, const float* __restrict__ U,
    const float* __restrict__ V,
    unsigned* __restrict__ htb, float* __restrict__ s2p,
    unsigned* __restrict__ Ub, unsigned* __restrict__ Vb,
    unsigned* __restrict__ cnt, float* __restrict__ out)
{
    __shared__ float hsh[2 * 128];     // h rows (f32, lives through epilogue) 1 KB
    __shared__ float ash[512];         // a[4][128]                            2 KB
    __shared__ float hts[2 * 256];     // ht rows f32                          2 KB
    __shared__ float s1sh[32];         // [r][g*4+hh]
    __shared__ float ewm[2 * 512];     // masked ew                            4 KB
    __shared__ float bias[2 * 512];    // 0 or -9e15                           4 KB
    __shared__ float s2sh[4 * 512];    // [hh][j]                              8 KB
    __shared__ float attwf[8 * 512];   // alpha exp f32 [rh][j]               16 KB
    __shared__ float invsh[8];
    __shared__ float scratch[4 * 256]; // partials, then psum                  4 KB
    __shared__ float csh[2 * 256];     // c rows                               2 KB

    const int t = threadIdx.x;
    const int i0 = blockIdx.x * 2;
    const int w = t >> 6, lane = t & 63;

    // ---------------- Phase A ----------------
    if (t < 64)       ((float4*)hsh)[t]      = ((const float4*)(h + i0 * 128))[t];
    else if (t < 192) ((float4*)ash)[t - 64] = ((const float4*)a)[t - 64];
    __syncthreads();

    // ht GEMM: 1 output/thread
    {
        const int r = t >> 8, col = t & 255;
        float acc = 0.f;
        const float4* Wv = (const float4*)(W + col * 128);
        const float* hp = hsh + r * 128;
        #pragma unroll
        for (int kk = 0; kk < 32; ++kk) {
            float4 w4 = Wv[kk];
            acc += w4.x * hp[kk*4] + w4.y * hp[kk*4+1] + w4.z * hp[kk*4+2] + w4.w * hp[kk*4+3];
        }
        hts[r * 256 + col] = acc;
    }
    // prefetch adj/ew for own 2 rows (latency hidden under pack/dots/barrier)
    const int pr = t >> 8, pj = (t & 255) * 2;
    int2   pav = *(const int2*)  (adj + (i0 + pr) * 512 + pj);
    float2 pwv = *(const float2*)(ew  + (i0 + pr) * 512 + pj);
    __syncthreads();

    if (t < 256) {   // htb pack: j-pair (2b lo, 2b+1 hi), feature t
        htb[blockIdx.x * 256 + t] = bf16rn(hts[t]) | (bf16rn(hts[256 + t]) << 16);
    } else if (t < 448) {   // Ub/Vb pack: 192 u32 per block
        const int idx = blockIdx.x * 192 + (t - 256);
        if (idx < 16384) {
            float2 f = ((const float2*)U)[idx];
            Ub[idx] = bf16rn(f.x) | (bf16rn(f.y) << 16);
        } else {
            float2 f = ((const float2*)V)[idx - 16384];
            Vb[idx - 16384] = bf16rn(f.x) | (bf16rn(f.y) << 16);
        }
    } else if (t < 488) {   // 40 dots -> s1 (LDS), s2 (global)
        const int tt = t - 448, rr = tt & 1, o = tt >> 1;
        const float* x;
        const float* y;
        if (o < 16) { x = hts + rr * 256 + (o >> 2) * 64;  y = ash + (o & 3) * 128; }
        else        { x = hts + rr * 256 + (o - 16) * 64;  y = ash + (o - 16) * 128 + 64; }
        float s = 0.f;
        #pragma unroll
        for (int ff = 0; ff < 64; ++ff) {
            int f = (ff + (tt << 3)) & 63;   // stagger
            s += x[f] * y[f];
        }
        if (o < 16) s1sh[rr * 16 + (o >> 2) * 4 + (o & 3)] = s;
        else        s2p[(o - 16) * 512 + i0 + rr] = s;
    }
    // mask/weight precompute into LDS
    ewm[pr * 512 + pj]      = (pav.x > 0) ? pwv.x : 0.f;
    ewm[pr * 512 + pj + 1]  = (pav.y > 0) ? pwv.y : 0.f;
    bias[pr * 512 + pj]     = (pav.x > 0) ? 0.f : -9.0e15f;
    bias[pr * 512 + pj + 1] = (pav.y > 0) ? 0.f : -9.0e15f;

    // ---------------- global barrier (arrival counter) ----------------
    __threadfence();
    __syncthreads();
    if (t == 0) {
        atomicAdd(cnt, 1u);
        while (__hip_atomic_load(cnt, __ATOMIC_ACQUIRE, __HIP_MEMORY_SCOPE_AGENT) < 256u)
            __builtin_amdgcn_s_sleep(8);
    }
    __syncthreads();
    __threadfence();

    // ---------------- Phase B ----------------
    ((float4*)s2sh)[t] = ((const float4*)s2p)[t];   // 2048 floats
    __syncthreads();

    // scores + softmax in-register: wave = (r = w>>2, hh = w&3), lane = 8 j
    {
        const int r = w >> 2, hh = w & 3;
        const int j0 = lane * 8;
        const float s1v = s1sh[r * 16 + (lane >> 4) * 4 + hh];
        float v[8];
        #pragma unroll
        for (int q = 0; q < 2; ++q) {
            const int jq = j0 + q * 4;
            float4 sv = *(const float4*)&s2sh[hh * 512 + jq];
            float4 em = *(const float4*)&ewm[r * 512 + jq];
            float4 bi = *(const float4*)&bias[r * 512 + jq];
            float e;
            e = s1v + sv.x; e = (e >= 0.f) ? e : 0.2f * e; v[q*4+0] = e * em.x + bi.x;
            e = s1v + sv.y; e = (e >= 0.f) ? e : 0.2f * e; v[q*4+1] = e * em.y + bi.y;
            e = s1v + sv.z; e = (e >= 0.f) ? e : 0.2f * e; v[q*4+2] = e * em.z + bi.z;
            e = s1v + sv.w; e = (e >= 0.f) ? e : 0.2f * e; v[q*4+3] = e * em.w + bi.w;
        }
        float m = v[0];
        #pragma unroll
        for (int k = 1; k < 8; ++k) m = fmaxf(m, v[k]);
        m = wave_max(m);
        float s = 0.f;
        #pragma unroll
        for (int k = 0; k < 8; ++k) { v[k] = __expf(v[k] - m); s += v[k]; }
        s = wave_sum(s);
        if (lane == 0) invsh[w] = 1.f / s;
        *(float4*)&attwf[w * 512 + j0]     = make_float4(v[0], v[1], v[2], v[3]);
        *(float4*)&attwf[w * 512 + j0 + 4] = make_float4(v[4], v[5], v[6], v[7]);
    }
    __syncthreads();

    // aggregate: wave = (hh = w&3, j-half jh = w>>2), both rows; f = lane
    {
        const int hh = w & 3, jh = w >> 2;
        float p0 = 0.f, p1 = 0.f;
        const unsigned* hb = htb + hh * 64 + lane;
        const int jp0 = jh * 128;
        for (int c8 = 0; c8 < 128; c8 += 8) {
            unsigned hv[8];
            #pragma unroll
            for (int u = 0; u < 8; ++u) hv[u] = hb[(jp0 + c8 + u) * 256];
            const int jj = 2 * (jp0 + c8);   // 16 consecutive j
            #pragma unroll
            for (int u = 0; u < 8; u += 2) {
                float4 a0 = *(const float4*)&attwf[hh * 512 + jj + 2 * u];
                float4 a1 = *(const float4*)&attwf[(4 + hh) * 512 + jj + 2 * u];
                float l0 = asf(hv[u] << 16),     h0v = asf(hv[u] & 0xffff0000u);
                float l1 = asf(hv[u+1] << 16),   h1v = asf(hv[u+1] & 0xffff0000u);
                p0 += a0.x * l0 + a0.y * h0v + a0.z * l1 + a0.w * h1v;
                p1 += a1.x * l0 + a1.y * h0v + a1.z * l1 + a1.w * h1v;
            }
        }
        scratch[(jh * 2 + 0) * 256 + hh * 64 + lane] = p0;
        scratch[(jh * 2 + 1) * 256 + hh * 64 + lane] = p1;
    }
    __syncthreads();

    // combine -> c rows
    {
        const int r = t >> 8, cc = t & 255;
        float cv = scratch[r * 256 + cc] + scratch[(2 + r) * 256 + cc];
        csh[r * 256 + cc] = cv * invsh[r * 4 + (cc >> 6)];
    }
    __syncthreads();

    // epilogue: thread = (K-half = t>>8, col = t&255), both rows
    {
        const int half = t >> 8, col = t & 255;
        float acc0 = 0.f, acc1 = 0.f;
        const uint4* Up = (const uint4*)(Ub + col * 64 + half * 32);
        #pragma unroll
        for (int b4 = 0; b4 < 8; ++b4) {
            uint4 uv = Up[b4];
            unsigned ua[4] = {uv.x, uv.y, uv.z, uv.w};
            #pragma unroll
            for (int e = 0; e < 4; ++e) {
                const int k = half * 64 + b4 * 8 + e * 2;
                float ulo = asf(ua[e] << 16), uhi = asf(ua[e] & 0xffff0000u);
                acc0 += ulo * hsh[k]       + uhi * hsh[k + 1];
                acc1 += ulo * hsh[128 + k] + uhi * hsh[128 + k + 1];
            }
        }
        const uint4* Vp = (const uint4*)(Vb + col * 128 + half * 64);
        #pragma unroll
        for (int b4 = 0; b4 < 16; ++b4) {
            uint4 vv = Vp[b4];
            unsigned va[4] = {vv.x, vv.y, vv.z, vv.w};
            #pragma unroll
            for (int e = 0; e < 4; ++e) {
                const int k = half * 128 + b4 * 8 + e * 2;
                float vlo = asf(va[e] << 16), vhi = asf(va[e] & 0xffff0000u);
                acc0 += vlo * csh[k]       + vhi * csh[k + 1];
                acc1 += vlo * csh[256 + k] + vhi * csh[256 + k + 1];
            }
        }
        scratch[(half * 2 + 0) * 256 + col] = acc0;
        scratch[(half * 2 + 1) * 256 + col] = acc1;
    }
    __syncthreads();
    {
        const int r = t >> 8, col = t & 255;
        float x = scratch[r * 256 + col] + scratch[(2 + r) * 256 + col];
        out[(i0 + r) * 256 + col] = 1.f / (1.f + __expf(-x));
    }
}

extern "C" void kernel_launch(void* const* d_in, const int* in_sizes, int n_in,
                              void* d_out, int out_size, void* d_ws, size_t ws_size,
                              hipStream_t stream) {
    const float* h   = (const float*)d_in[0];
    const int*   adj = (const int*)d_in[1];
    const float* ew  = (const float*)d_in[2];
    const float* W   = (const float*)d_in[3];
    const float* a   = (const float*)d_in[4];
    const float* U   = (const float*)d_in[5];
    const float* V   = (const float*)d_in[6];
    float* out = (float*)d_out;

    unsigned* htb = (unsigned*)d_ws;          // 65536 u32 (ht bf16 j-pairs)
    float* s2p    = (float*)(htb + 65536);    // 4*512 f32
    unsigned* Ub  = (unsigned*)(s2p + 2048);  // 16384 u32
    unsigned* Vb  = Ub + 16384;               // 32768 u32
    unsigned* cnt = Vb + 32768;               // barrier counter

    hipMemsetAsync((void*)cnt, 0, 4, stream);
    k_mono<<<256, 512, 0, stream>>>(h, adj, ew, W, a, U, V,
                                    htb, s2p, Ub, Vb, cnt, out);
}

// Round 11
// 48.399 us; speedup vs baseline: 2.1879x; 2.1879x over previous
//
#include <hip/hip_runtime.h>
#include <math.h>

// N=512, IN_F=128, OUT_F=64, H=4.
// SINGLE-NODE kernel: no inter-block dependency. Each block (8 output rows)
// redundantly computes the full ht = h@W^T via bf16 MFMA (33.5 MFLOP), does
// fixed-shift softmax (no max subtraction; masked -> exp -> 0 exactly), then
// num = E@HT and out = sigmoid([h|c]@[U;V]^T), all via mfma_f32_16x16x32_bf16.
// s2 = h @ wa2^T with wa2[h,k] = sum_f W[h*64+f,k]*a[h,64+f];
// s1[r][g][h] = dot(ht[own_row][g*64:], a[h][:64]) from own ht rows.

typedef short short8 __attribute__((ext_vector_type(8)));
typedef float f32x4 __attribute__((ext_vector_type(4)));

union ABu { uint4 u; short8 v; };
union CDu { f32x4 v; float f[4]; };

#define MFMA(a,b,c) __builtin_amdgcn_mfma_f32_16x16x32_bf16((a),(b),(c),0,0,0)

// pack two f32 into bf16x2 u32 (round-half-up): low short = lo
__device__ __forceinline__ unsigned pk2(float lo, float hi) {
    return __builtin_amdgcn_perm(__float_as_uint(hi) + 0x8000u,
                                 __float_as_uint(lo) + 0x8000u, 0x07060302u);
}
__device__ __forceinline__ ushort bf1(float x) {
    return (ushort)((__float_as_uint(x) + 0x8000u) >> 16);
}
__device__ __forceinline__ float wsum(float v) {
    #pragma unroll
    for (int o = 32; o; o >>= 1) v += __shfl_xor(v, o, 64);
    return v;
}
// swizzled byte offset within a row: XOR bits 4-6 by (row&7)
#define SWZ(row, cbyte) ((cbyte) ^ (((row) & 7) << 4))

__global__ __launch_bounds__(512) void k_mono(
    const float* __restrict__ h, const int* __restrict__ adj,
    const float* __restrict__ ew, const float* __restrict__ W,
    const float* __restrict__ a, const float* __restrict__ U,
    const float* __restrict__ V, float* __restrict__ out)
{
    __shared__ __align__(16) ushort hA[128 * 128];   // 32 KB [jloc][k] bf16 swz
    __shared__ __align__(16) ushort htT[256 * 128];  // 64 KB [feat][jloc] swz
    __shared__ __align__(16) ushort E32[32 * 128];   //  8 KB [h*8+r][jloc] swz
    __shared__ __align__(16) ushort Xs[16 * 384];    // 12 KB [row][k] swz (768B)
    __shared__ __align__(16) ushort w2T[16 * 128];   //  4 KB [h pad16][k] swz
    __shared__ float s2c[4 * 128];                   // [h][jloc]
    __shared__ float s1s[8 * 16];                    // [r][g*4+h]
    __shared__ float ash[512];                       // a[4][128]
    __shared__ float dacc[32], dinv[32];

    const int t = threadIdx.x;
    const int l = t & 63, w = t >> 6;
    const int i0 = blockIdx.x * 8;
    const int co = i0 >> 7;   // chunk containing own rows

    // ---------------- P0 ----------------
    if (t < 128) ((float4*)ash)[t] = ((const float4*)a)[t];
    if (t < 32) dacc[t] = 0.f;
    {   // zero Xs (rows 8-15 must stay zero; zero it all)
        uint4 z = make_uint4(0u, 0u, 0u, 0u);
        for (int q = t; q < 768; q += 512) ((uint4*)Xs)[q] = z;
    }
    __syncthreads();
    if (t < 128) {   // wa2 -> w2T rows 0-3 (bf16, swizzled)
        const int hh = t >> 5, k4 = (t & 31) * 4;
        float s0 = 0.f, s1v = 0.f, s2v = 0.f, s3v = 0.f;
        for (int f = 0; f < 64; ++f) {
            float av = ash[hh * 128 + 64 + f];
            const float* wp = W + (hh * 64 + f) * 128 + k4;
            s0 += wp[0] * av; s1v += wp[1] * av; s2v += wp[2] * av; s3v += wp[3] * av;
        }
        *(uint2*)((char*)w2T + hh * 256 + SWZ(hh, k4 * 2)) =
            make_uint2(pk2(s0, s1v), pk2(s2v, s3v));
    } else if (t >= 128 && t < 320) {   // zero w2T rows 4-15
        ((uint4*)((char*)w2T + 4 * 256))[t - 128] = make_uint4(0u, 0u, 0u, 0u);
    }

    // GEMM-2 accumulators (persist across chunks): wave -> (mt2, 2 n-tiles)
    f32x4 c2a = {0.f, 0.f, 0.f, 0.f}, c2b = {0.f, 0.f, 0.f, 0.f};
    const int mt2 = w >> 2;
    const int ntA = mt2 * 8 + (w & 3) * 2, ntB = ntA + 1;

    for (int cc = 0; cc < 4; ++cc) {
        const int ch = (co + cc) & 3;     // own chunk first (s1 availability)
        const int jg0 = ch * 128;
        __syncthreads();                  // htT/hA free (prev GEMM-2 done)

        {   // stage hA: thread = (row = t>>2, k0 = (t&3)*32)
            const int row = t >> 2, k0 = (t & 3) * 32;
            const float* hp = h + (jg0 + row) * 128 + k0;
            char* dst = (char*)hA + row * 256;
            #pragma unroll
            for (int kk = 0; kk < 32; kk += 8) {
                float4 f0 = *(const float4*)(hp + kk);
                float4 f1 = *(const float4*)(hp + kk + 4);
                *(uint4*)(dst + SWZ(row, (k0 + kk) * 2)) =
                    make_uint4(pk2(f0.x, f0.y), pk2(f0.z, f0.w),
                               pk2(f1.x, f1.y), pk2(f1.z, f1.w));
            }
        }
        __syncthreads();

        {   // GEMM-1: HT[j][m] = sum_k h[j,k] W[m,k]; wave = (jh = w>>2, nq = w&3)
            const int jh = w >> 2, nq = w & 3;
            f32x4 c1[4][4];
            #pragma unroll
            for (int x = 0; x < 4; ++x)
                #pragma unroll
                for (int y = 0; y < 4; ++y) c1[x][y] = f32x4{0.f, 0.f, 0.f, 0.f};
            f32x4 cs2[4];
            #pragma unroll
            for (int x = 0; x < 4; ++x) cs2[x] = f32x4{0.f, 0.f, 0.f, 0.f};

            #pragma unroll
            for (int ks = 0; ks < 4; ++ks) {
                const int kb = ks * 32 + ((l >> 4) * 8);
                short8 Af[4];
                #pragma unroll
                for (int jj = 0; jj < 4; ++jj) {
                    int row = (jh * 4 + jj) * 16 + (l & 15);
                    Af[jj] = *(const short8*)((const char*)hA + row * 256 + SWZ(row, kb * 2));
                }
                #pragma unroll
                for (int nn = 0; nn < 4; ++nn) {
                    int m = (nq * 4 + nn) * 16 + (l & 15);
                    const float* wp = W + m * 128 + kb;
                    float4 f0 = *(const float4*)wp;
                    float4 f1 = *(const float4*)(wp + 4);
                    ABu B; B.u = make_uint4(pk2(f0.x, f0.y), pk2(f0.z, f0.w),
                                            pk2(f1.x, f1.y), pk2(f1.z, f1.w));
                    #pragma unroll
                    for (int jj = 0; jj < 4; ++jj)
                        c1[jj][nn] = MFMA(Af[jj], B.v, c1[jj][nn]);
                }
                if (nq == 0) {   // s2 = hA @ wa2^T on the nq==0 waves
                    int rr = l & 15;
                    short8 Bw = *(const short8*)((const char*)w2T + rr * 256 + SWZ(rr, kb * 2));
                    #pragma unroll
                    for (int jj = 0; jj < 4; ++jj)
                        cs2[jj] = MFMA(Af[jj], Bw, cs2[jj]);
                }
            }
            // write ht tiles -> htT[feat][jloc] bf16 swz
            #pragma unroll
            for (int jj = 0; jj < 4; ++jj) {
                #pragma unroll
                for (int nn = 0; nn < 4; ++nn) {
                    int feat = (nq * 4 + nn) * 16 + (l & 15);
                    int j4 = (jh * 4 + jj) * 16 + ((l >> 4) * 4);
                    CDu cd; cd.v = c1[jj][nn];
                    *(uint2*)((char*)htT + feat * 256 + SWZ(feat, j4 * 2)) =
                        make_uint2(pk2(cd.f[0], cd.f[1]), pk2(cd.f[2], cd.f[3]));
                }
            }
            if (nq == 0 && (l & 15) < 4) {   // s2c[h][jloc]
                int hh = l & 15;
                #pragma unroll
                for (int jj = 0; jj < 4; ++jj) {
                    int j4 = (jh * 4 + jj) * 16 + (l >> 4) * 4;
                    CDu cd; cd.v = cs2[jj];
                    #pragma unroll
                    for (int q = 0; q < 4; ++q) s2c[hh * 128 + j4 + q] = cd.f[q];
                }
            }
        }
        __syncthreads();

        if (cc == 0) {   // s1 from own ht rows (this chunk contains them)
            if (t < 128) {
                const int r = t >> 4, gh = t & 15, g = gh >> 2, hh = gh & 3;
                const int jl = (i0 - jg0) + r;
                float s = 0.f;
                for (int f = 0; f < 64; ++f) {
                    int feat = g * 64 + f;
                    ushort uv = *(const ushort*)((const char*)htT + feat * 256 + SWZ(feat, jl * 2));
                    s += __uint_as_float(((unsigned)uv) << 16) * ash[hh * 128 + f];
                }
                s1s[r * 16 + gh] = s;
            }
            __syncthreads();
        }

        {   // scores + exp -> E32; wave = row r = w; lane: 2 consecutive j
            const int r = w, jl = l * 2;
            int2   av = *(const int2*)  (adj + (i0 + r) * 512 + jg0 + jl);
            float2 wv = *(const float2*)(ew  + (i0 + r) * 512 + jg0 + jl);
            float rs[4];
            #pragma unroll
            for (int hh = 0; hh < 4; ++hh) {
                float s1v = s1s[r * 16 + ch * 4 + hh];
                float e0 = s1v + s2c[hh * 128 + jl];
                float e1 = s1v + s2c[hh * 128 + jl + 1];
                e0 = (e0 >= 0.f) ? e0 : 0.2f * e0;
                e1 = (e1 >= 0.f) ? e1 : 0.2f * e1;
                e0 = (av.x > 0) ? e0 * wv.x : -9.0e15f;
                e1 = (av.y > 0) ? e1 * wv.y : -9.0e15f;
                float x0 = __expf(e0), x1 = __expf(e1);   // masked -> exactly 0
                rs[hh] = x0 + x1;
                int row32 = hh * 8 + r;
                *(unsigned*)((char*)E32 + row32 * 256 + SWZ(row32, jl * 2)) = pk2(x0, x1);
            }
            #pragma unroll
            for (int hh = 0; hh < 4; ++hh) {
                float s = wsum(rs[hh]);
                if (l == 0) dacc[hh * 8 + r] += s;
            }
        }
        __syncthreads();

        {   // GEMM-2: num += E32(mt2) @ htT(ntA/ntB), K = 128
            #pragma unroll
            for (int ks = 0; ks < 4; ++ks) {
                const int kb = ks * 32 + ((l >> 4) * 8);
                int rowA = mt2 * 16 + (l & 15);
                short8 Af = *(const short8*)((const char*)E32 + rowA * 256 + SWZ(rowA, kb * 2));
                int fA = ntA * 16 + (l & 15);
                short8 B0 = *(const short8*)((const char*)htT + fA * 256 + SWZ(fA, kb * 2));
                c2a = MFMA(Af, B0, c2a);
                int fB = ntB * 16 + (l & 15);
                short8 B1 = *(const short8*)((const char*)htT + fB * 256 + SWZ(fB, kb * 2));
                c2b = MFMA(Af, B1, c2b);
            }
        }
    }
    __syncthreads();

    // ---------------- epilogue ----------------
    if (t < 32) dinv[t] = 1.f / dacc[t];
    {   // X h-part: rows 0-7, k 0-127
        const int r = w, k2 = l * 2;
        float2 f = *(const float2*)(h + (i0 + r) * 128 + k2);
        *(unsigned*)((char*)Xs + r * 768 + SWZ(r, k2 * 2)) = pk2(f.x, f.y);
    }
    __syncthreads();
    {   // X c-part from GEMM-2 accumulators (valid quadrants only)
        #pragma unroll
        for (int tt = 0; tt < 2; ++tt) {
            int nt = tt ? ntB : ntA;
            int hd = nt >> 2;                      // head of this n-tile
            CDu cd; cd.v = tt ? c2b : c2a;
            #pragma unroll
            for (int q = 0; q < 4; ++q) {
                int row32 = mt2 * 16 + (l >> 4) * 4 + q;
                if ((row32 >> 3) == hd) {          // E32 row's head matches
                    int r = row32 & 7;
                    int kx = 128 + nt * 16 + (l & 15);   // c section: 128 + h*64+f
                    float val = cd.f[q] * dinv[row32];
                    *(ushort*)((char*)Xs + r * 768 + SWZ(r, kx * 2)) = bf1(val);
                }
            }
        }
    }
    __syncthreads();
    {   // GEMM-3: out = sigmoid(X(16x384) @ [U;V]^T); wave: n-tiles 2w, 2w+1
        f32x4 c3a = {0.f, 0.f, 0.f, 0.f}, c3b = {0.f, 0.f, 0.f, 0.f};
        const int n0 = (w * 2) * 16 + (l & 15), n1 = n0 + 16;
        #pragma unroll
        for (int ks = 0; ks < 12; ++ks) {
            const int kb = ks * 32 + ((l >> 4) * 8);
            int rowA = l & 15;
            short8 Af = *(const short8*)((const char*)Xs + rowA * 768 + SWZ(rowA, kb * 2));
            const float* p0 = (ks < 4) ? (U + n0 * 128 + kb) : (V + n0 * 256 + (kb - 128));
            const float* p1 = (ks < 4) ? (U + n1 * 128 + kb) : (V + n1 * 256 + (kb - 128));
            float4 f0 = *(const float4*)p0, f1 = *(const float4*)(p0 + 4);
            ABu B0; B0.u = make_uint4(pk2(f0.x, f0.y), pk2(f0.z, f0.w),
                                      pk2(f1.x, f1.y), pk2(f1.z, f1.w));
            c3a = MFMA(Af, B0.v, c3a);
            float4 g0 = *(const float4*)p1, g1 = *(const float4*)(p1 + 4);
            ABu B1; B1.u = make_uint4(pk2(g0.x, g0.y), pk2(g0.z, g0.w),
                                      pk2(g1.x, g1.y), pk2(g1.z, g1.w));
            c3b = MFMA(Af, B1.v, c3b);
        }
        CDu ca, cb; ca.v = c3a; cb.v = c3b;
        #pragma unroll
        for (int q = 0; q < 4; ++q) {
            int row = (l >> 4) * 4 + q;
            if (row < 8) {
                out[(i0 + row) * 256 + n0]      = 1.f / (1.f + __expf(-ca.f[q]));
                out[(i0 + row) * 256 + n1]      = 1.f / (1.f + __expf(-cb.f[q]));
            }
        }
    }
}

extern "C" void kernel_launch(void* const* d_in, const int* in_sizes, int n_in,
                              void* d_out, int out_size, void* d_ws, size_t ws_size,
                              hipStream_t stream) {
    const float* h   = (const float*)d_in[0];
    const int*   adj = (const int*)d_in[1];
    const float* ew  = (const float*)d_in[2];
    const float* W   = (const float*)d_in[3];
    const float* a   = (const float*)d_in[4];
    const float* U   = (const float*)d_in[5];
    const float* V   = (const float*)d_in[6];
    float* out = (float*)d_out;

    k_mono<<<64, 512, 0, stream>>>(h, adj, ew, W, a, U, V, out);
}

// Round 12
// 45.040 us; speedup vs baseline: 2.3510x; 1.0746x over previous
//
#include <hip/hip_runtime.h>
#include <math.h>

// N=512, IN_F=128, OUT_F=64, H=4.
// SINGLE-NODE kernel, 128 blocks x 512 thr (8 waves), block = 4 output rows.
// Associativity: c = (alpha@h)@W^T -- no redundant full-ht GEMM.
//   wa1[g*4+h][k] = sum_f W[g*64+f,k]*a[h,f]      (s1 = h_own @ wa1^T)
//   wa2[h][k]     = sum_f W[h*64+f,k]*a[h,64+f]   (s2 = h @ wa2^T, all j)
//   E[rh,j] = exp(mask(leaky(s1+s2)*ew))  (no max-sub: masked -> exp(-9e15)=0)
//   g[rh,k] = sum_j E[rh,j] h[j,k]   (chunked j, MFMA, acc in VGPR)
//   c = (g * 1/sum_j E) @ W^T ; out = sigmoid([h_own|c] @ [U|V]^T)
// All MFMA frag conventions identical to the round-11 kernel (HW-verified):
//   A-frag m=lane&15, k=(lane>>4)*8+reg contig; B-frag n=lane&15 same k;
//   D col=lane&15, row=(lane>>4)*4+q.
// LDS rows padded to pitch = 16B*odd (272/144/784B) -> 2-way bank aliasing (free).

typedef short short8 __attribute__((ext_vector_type(8)));
typedef float f32x4 __attribute__((ext_vector_type(4)));
union CDu { f32x4 v; float f[4]; };

#define MFMA(a,b,c) __builtin_amdgcn_mfma_f32_16x16x32_bf16((a),(b),(c),0,0,0)

__device__ __forceinline__ unsigned pk2(float lo, float hi) {
    return __builtin_amdgcn_perm(__float_as_uint(hi) + 0x8000u,
                                 __float_as_uint(lo) + 0x8000u, 0x07060302u);
}
__device__ __forceinline__ ushort bf1(float x) {
    return (ushort)((__float_as_uint(x) + 0x8000u) >> 16);
}
__device__ __forceinline__ float unbf(ushort u) {
    return __uint_as_float(((unsigned)u) << 16);
}
__device__ __forceinline__ float wsum(float v) {
    #pragma unroll
    for (int o = 32; o; o >>= 1) v += __shfl_xor(v, o, 64);
    return v;
}

// LDS layout (138,880 B):
//   [0      ) Wb  [256][136]u16 (272B rows)  69632   \ overlaid by
//   [69632  ) hA  [64][136]u16               17408    | UVb [128][392]u16
//   [87040  ) hT  [128][72]u16 (144B rows)   18432   /  (784B rows, 100352B)
//   [105472 ) Eb  [16][72]u16                 2304
//   [107776 ) wab [32][136]u16                8704
//   [116480 ) gsb [16][136]u16                4352
//   [120832 ) Xsb [16][392]u16 (784B rows)   12544
//   [133376 ) s2c [4][64]f32                  1024
//   [134400 ) ash [512]f32                    2048
//   [136448 ) hown[4][128]f32                 2048
//   [138496 ) s1s [64]f32                      256
//   [138752 ) dacc[16]f32 ; [138816) dinv[16]f32

__global__ __launch_bounds__(512) void k_mono(
    const float* __restrict__ h, const int* __restrict__ adj,
    const float* __restrict__ ew, const float* __restrict__ W,
    const float* __restrict__ a, const float* __restrict__ U,
    const float* __restrict__ V, float* __restrict__ out)
{
    __shared__ __align__(16) char L[138880];
    const int t = threadIdx.x, l = t & 63, w = t >> 6;
    const int i0 = blockIdx.x * 4;

    char* Wb  = L;
    char* hA  = L + 69632;
    char* hT  = L + 87040;
    char* UVb = L;              // overlay (Wb/hA/hT dead by epilogue)
    char* Eb  = L + 105472;
    char* wab = L + 107776;
    char* gsb = L + 116480;
    char* Xsb = L + 120832;
    float* s2c  = (float*)(L + 133376);
    float* ash  = (float*)(L + 134400);
    float* hown = (float*)(L + 136448);
    float* s1s  = (float*)(L + 138496);
    float* dacc = (float*)(L + 138752);
    float* dinv = (float*)(L + 138816);

    // ---------------- P0: zero + stage ----------------
    for (int q = t; q < 3136; q += 512) ((unsigned*)Xsb)[q] = 0u;   // Xs rows 4-15 must be 0
    for (int q = t; q < 2176; q += 512) ((unsigned*)wab)[q] = 0u;   // wa rows 20-31 must be 0
    if (t < 16) dacc[t] = 0.f;
    if (t < 128) ((float4*)ash)[t] = ((const float4*)a)[t];
    if (t >= 128 && t < 384) {      // own h rows: f32 copy + bf16 into Xs
        int i = t - 128, r = i >> 6, k2 = (i & 63) * 2;
        float2 f = *(const float2*)(h + (i0 + r) * 128 + k2);
        hown[r * 128 + k2] = f.x;  hown[r * 128 + k2 + 1] = f.y;
        *(unsigned*)(Xsb + r * 784 + k2 * 2) = pk2(f.x, f.y);
    }
    #pragma unroll
    for (int it = 0; it < 16; ++it) {   // W -> Wb bf16, coalesced, read once
        int lin = it * 512 + t, feat = lin >> 5, f4 = lin & 31;
        float4 wv = *(const float4*)(W + feat * 128 + f4 * 4);
        *(uint2*)(Wb + feat * 272 + f4 * 8) =
            make_uint2(pk2(wv.x, wv.y), pk2(wv.z, wv.w));
    }
    __syncthreads();

    {   // wa1 (rows 0-15) and wa2 (rows 16-19) from Wb, lanes = k (coalesced LDS)
        int k = t & 127, grp = t >> 7;
        for (int row = grp; row < 20; row += 4) {
            float acc = 0.f;
            if (row < 16) {
                int g = row >> 2, hh = row & 3;
                for (int f = 0; f < 64; ++f)
                    acc += unbf(*(const ushort*)(Wb + (g * 64 + f) * 272 + k * 2))
                           * ash[hh * 128 + f];
            } else {
                int hh = row - 16;
                for (int f = 0; f < 64; ++f)
                    acc += unbf(*(const ushort*)(Wb + (hh * 64 + f) * 272 + k * 2))
                           * ash[hh * 128 + 64 + f];
            }
            *(ushort*)(wab + row * 272 + k * 2) = bf1(acc);
        }
    }
    __syncthreads();

    if (t < 64) {   // s1[r][gh] = hown[r] . wa1[gh]
        int r = t >> 4, gh = t & 15;
        float s = 0.f;
        for (int k = 0; k < 128; ++k)
            s += hown[r * 128 + k] * unbf(*(const ushort*)(wab + gh * 272 + k * 2));
        s1s[r * 16 + gh] = s;
    }

    f32x4 gacc = {0.f, 0.f, 0.f, 0.f};   // g accumulator: wave w = k-dims w*16..+15

    // ---------------- chunk loop: 8 x 64 j ----------------
    for (int c = 0; c < 8; ++c) {
        const int jg = c * 64;
        __syncthreads();   // prev chunk's g-GEMM done -> hA/hT free
        #pragma unroll
        for (int it = 0; it < 4; ++it) {   // stage h chunk -> hA[j][k], hT[k][j]
            int lin = it * 512 + t, row = lin >> 5, f4 = lin & 31;
            float4 hv = *(const float4*)(h + (jg + row) * 128 + f4 * 4);
            *(uint2*)(hA + row * 272 + f4 * 8) =
                make_uint2(pk2(hv.x, hv.y), pk2(hv.z, hv.w));
            int k = f4 * 4;
            *(ushort*)(hT + (k + 0) * 144 + row * 2) = bf1(hv.x);
            *(ushort*)(hT + (k + 1) * 144 + row * 2) = bf1(hv.y);
            *(ushort*)(hT + (k + 2) * 144 + row * 2) = bf1(hv.z);
            *(ushort*)(hT + (k + 3) * 144 + row * 2) = bf1(hv.w);
        }
        __syncthreads();

        if (w < 4) {   // s2 chunk: s2[j][h] = hA @ wa2^T (wa rows 16-19)
            f32x4 cs = {0.f, 0.f, 0.f, 0.f};
            #pragma unroll
            for (int ks = 0; ks < 4; ++ks) {
                int kb = ks * 32 + (l >> 4) * 8;
                short8 Af = *(const short8*)(hA + (w * 16 + (l & 15)) * 272 + kb * 2);
                short8 Bf = *(const short8*)(wab + (16 + (l & 15)) * 272 + kb * 2);
                cs = MFMA(Af, Bf, cs);
            }
            if ((l & 15) < 4) {
                CDu cd; cd.v = cs;
                int hh = l & 15;
                #pragma unroll
                for (int q = 0; q < 4; ++q)
                    s2c[hh * 64 + w * 16 + (l >> 4) * 4 + q] = cd.f[q];
            }
        }
        __syncthreads();

        {   // scores + exp -> Eb, denom partials; wave: r = w&3, heads 2(w>>2)+{0,1}
            int r = w & 3, hp = w >> 2, g = c >> 1;
            int   ad = adj[(i0 + r) * 512 + jg + l];
            float ev = ew [(i0 + r) * 512 + jg + l];
            #pragma unroll
            for (int hi = 0; hi < 2; ++hi) {
                int hh = hp * 2 + hi;
                float e = s1s[r * 16 + g * 4 + hh] + s2c[hh * 64 + l];
                e = (e >= 0.f) ? e : 0.2f * e;
                e = (ad > 0) ? e * ev : -9.0e15f;
                float x = __expf(e);
                *(ushort*)(Eb + (hh * 4 + r) * 144 + l * 2) = bf1(x);
                float s = wsum(x);
                if (l == 0) dacc[hh * 4 + r] += s;
            }
        }
        __syncthreads();

        #pragma unroll
        for (int ks = 0; ks < 2; ++ks) {   // g += E(16 x 64j) @ hT(64j x 128k)
            int kb = ks * 32 + (l >> 4) * 8;
            short8 Af = *(const short8*)(Eb + (l & 15) * 144 + kb * 2);
            short8 Bf = *(const short8*)(hT + (w * 16 + (l & 15)) * 144 + kb * 2);
            gacc = MFMA(Af, Bf, gacc);
        }
    }
    __syncthreads();
    if (t < 16) dinv[t] = 1.f / dacc[t];
    __syncthreads();

    {   // gs[rh][k] = g * dinv (bf16)
        CDu cd; cd.v = gacc;
        #pragma unroll
        for (int q = 0; q < 4; ++q) {
            int rh = (l >> 4) * 4 + q;
            *(ushort*)(gsb + rh * 272 + (w * 16 + (l & 15)) * 2) =
                bf1(cd.f[q] * dinv[rh]);
        }
    }
    __syncthreads();

    #pragma unroll
    for (int tt = 0; tt < 2; ++tt) {   // c = gs @ W^T; keep head-matching quadrant
        int nt = w * 2 + tt, head = nt >> 2;
        f32x4 cc = {0.f, 0.f, 0.f, 0.f};
        #pragma unroll
        for (int ks = 0; ks < 4; ++ks) {
            int kb = ks * 32 + (l >> 4) * 8;
            short8 Af = *(const short8*)(gsb + (l & 15) * 272 + kb * 2);
            short8 Bf = *(const short8*)(Wb + (nt * 16 + (l & 15)) * 272 + kb * 2);
            cc = MFMA(Af, Bf, cc);
        }
        if ((l >> 4) == head) {   // rows rh = head*4+q -> r = q
            CDu cd; cd.v = cc;
            #pragma unroll
            for (int q = 0; q < 4; ++q)
                *(ushort*)(Xsb + q * 784 + 256 + (nt * 16 + (l & 15)) * 2) = bf1(cd.f[q]);
        }
    }

    // ---------------- epilogue: out = sigmoid(Xs @ [U|V]^T) ----------------
    for (int gp = 0; gp < 2; ++gp) {
        __syncthreads();   // Wb/hA/hT dead -> overlay UVb
        for (int it = 0; it < 24; ++it) {   // stage 128 cols x 384 k, coalesced
            int lin = it * 512 + t, row = lin / 96, q = lin % 96;
            const float* src = (q < 32) ? (U + (gp * 128 + row) * 128 + q * 4)
                                        : (V + (gp * 128 + row) * 256 + (q - 32) * 4);
            float4 f = *(const float4*)src;
            *(uint2*)(UVb + row * 784 + q * 8) =
                make_uint2(pk2(f.x, f.y), pk2(f.z, f.w));
        }
        __syncthreads();
        f32x4 co = {0.f, 0.f, 0.f, 0.f};
        #pragma unroll
        for (int ks = 0; ks < 12; ++ks) {
            int kb = ks * 32 + (l >> 4) * 8;
            short8 Af = *(const short8*)(Xsb + (l & 15) * 784 + kb * 2);
            short8 Bf = *(const short8*)(UVb + (w * 16 + (l & 15)) * 784 + kb * 2);
            co = MFMA(Af, Bf, co);
        }
        if ((l >> 4) == 0) {
            CDu cd; cd.v = co;
            #pragma unroll
            for (int q = 0; q < 4; ++q)
                out[(i0 + q) * 256 + gp * 128 + w * 16 + (l & 15)] =
                    1.f / (1.f + __expf(-cd.f[q]));
        }
    }
}

extern "C" void kernel_launch(void* const* d_in, const int* in_sizes, int n_in,
                              void* d_out, int out_size, void* d_ws, size_t ws_size,
                              hipStream_t stream) {
    const float* h   = (const float*)d_in[0];
    const int*   adj = (const int*)d_in[1];
    const float* ew  = (const float*)d_in[2];
    const float* W   = (const float*)d_in[3];
    const float* a   = (const float*)d_in[4];
    const float* U   = (const float*)d_in[5];
    const float* V   = (const float*)d_in[6];
    float* out = (float*)d_out;

    k_mono<<<128, 512, 0, stream>>>(h, adj, ew, W, a, U, V, out);
}